// Round 12
// baseline (327.875 us; speedup 1.0000x reference)
//
#include <hip/hip_runtime.h>
#include <cstdint>

// ---------------------------------------------------------------------------
// Round 25. r24 mega: 220.6 vs r23 215.5 -> gaps were never the big cost;
// dropped. Remaining lever: gemms 118us @ 327 TF (13% peak). Guide m230-V0:
// minimum-2-phase (stage-next FIRST, one drain per K-tile) at 256^2 tile is
// MEASURED at 682 TF / 5.3 TB/s staged with 1 block/CU on this chip — my
// r15 "failure" of the same schedule was at 128x256 (85 FLOP/B vs 128);
// the thin tile, not the schedule, was the flaw. Port gemms to 256^2:
// 512thr/8 waves (2m x 4n, 128x64/wave), BK=64, 128KB dyn-LDS dbuf, XOR
// swizzle, setprio, 4-quadrant fragment phasing (regs ~216, 1 block/CU).
// Staged bytes 295 -> 164 MB/gemm. Expert pads 128 -> 256 (soff align
// change only); NROWS 10240; workspace re-laid (ends 83MB < 86MB proven).
// gemm1 = 320 blocks; gemm2 = 2x40xsplitK4 = 320 blocks (same geometry).
// Predict: gemm 59 -> 32-42 each, MfmaUtil 25-35%, total ~170-190.
// Fail-mode: gemm >= 70 -> revert to r23 128^2 core.
// ---------------------------------------------------------------------------

#define T_TOK 4096
#define D_DIM 512
#define F_DIM 2048
#define E_EXP 8
#define NROWS 10240     // 8192 assignments + 8*256 pad (256-aligned buckets)
#define MT256 40        // NROWS / 256
#define RT_BLKS 64
#define TR_BLKS 4096
#define ZO_BLKS 1024
#define G1_TILES (8 * MT256)        // 320
#define G2_TILES (2 * MT256 * 4)    // 320 (splitK4)
#define GTILE (256 * 64)            // u16 elems per LDS tile buf (A or B)
#define GEMM_LDS (4 * GTILE * 2)    // 2 dbuf x (A+B) x 2B = 131072 = 128KB

typedef __bf16 bf16x8 __attribute__((ext_vector_type(8)));
typedef float  f32x4  __attribute__((ext_vector_type(4)));
typedef unsigned short u16;
typedef unsigned short u16x8 __attribute__((ext_vector_type(8)));

__device__ __forceinline__ u16 f2b(float f) {
    return __builtin_bit_cast(unsigned short, (__bf16)f);
}
__device__ __forceinline__ void gload16(void* lds, const void* g) {
    __builtin_amdgcn_global_load_lds(
        (const __attribute__((address_space(1))) void*)g,
        (__attribute__((address_space(3))) void*)lds, 16, 0, 0);
}
// tanh-approx GELU (err ~3e-4 << bf16 ulp)
__device__ __forceinline__ float gelu_f(float v) {
    float z = 0.7978845608f * (v + 0.044715f * v * v * v);
    float t = 1.0f - 2.0f / (1.0f + __expf(2.0f * z));
    return 0.5f * v * (1.0f + t);
}

// ---------------- transpose tile body (shared by pre_k) ---------------------
__device__ __forceinline__ void tbody(const float* __restrict__ in,
                                      u16* __restrict__ out, int R, int C,
                                      int c0, int r0, int tid,
                                      float (*t)[65]) {
    int cq = tid & 15, rb = tid >> 4;
#pragma unroll
    for (int pass = 0; pass < 4; ++pass) {
        int rr = rb + pass * 16;
        float4 v = *(const float4*)(in + (size_t)(r0 + rr) * C + c0 + cq * 4);
        t[rr][cq * 4 + 0] = v.x; t[rr][cq * 4 + 1] = v.y;
        t[rr][cq * 4 + 2] = v.z; t[rr][cq * 4 + 3] = v.w;
    }
    __syncthreads();
    int rg = tid & 15, cb = tid >> 4;
#pragma unroll
    for (int pass = 0; pass < 4; ++pass) {
        int c = cb + pass * 16;
        ushort4 o;
        o.x = f2b(t[rg * 4 + 0][c]); o.y = f2b(t[rg * 4 + 1][c]);
        o.z = f2b(t[rg * 4 + 2][c]); o.w = f2b(t[rg * 4 + 3][c]);
        *(ushort4*)(out + (size_t)(c0 + c) * R + r0 + rg * 4) = o;
    }
}

// ---------------- pre_k: routing + transposes + zero/init, ONE dispatch -----
#define PRE_BLOCKS (RT_BLKS + TR_BLKS + ZO_BLKS + 1)

__global__ void pre_k(const float* __restrict__ x, const float* __restrict__ anchors,
                      const float* __restrict__ W1, u16* __restrict__ W1T,
                      const float* __restrict__ W2, u16* __restrict__ W2T,
                      float* __restrict__ outm, float* __restrict__ dout_an,
                      float* __restrict__ dout_scores, float* __restrict__ dout_idx,
                      int* __restrict__ idxs, float* __restrict__ gates,
                      int* __restrict__ cnthist, int* __restrict__ ranks,
                      int* __restrict__ rowmap, float* __restrict__ rowgate) {
    __shared__ float shpool[E_EXP * 544];   // routing: anl; transpose: 64x65
    __shared__ int hist[E_EXP];
    int b = blockIdx.x;
    int tid = threadIdx.x;

    if (b >= RT_BLKS + TR_BLKS + ZO_BLKS) {             // ---- misc init ----
        for (int r = tid; r < NROWS; r += 256) {
            rowmap[r] = -1; rowgate[r] = 0.f;
        }
        return;
    }
    if (b >= RT_BLKS + TR_BLKS) {                       // ---- zero outm ----
        int zb = b - (RT_BLKS + TR_BLKS);
        float4* o4 = (float4*)outm;
        int i = zb * 256 + tid;
        o4[i] = float4{0.f, 0.f, 0.f, 0.f};
        o4[i + ZO_BLKS * 256] = float4{0.f, 0.f, 0.f, 0.f};
        return;
    }
    if (b >= RT_BLKS) {                                 // ---- transposes ----
        float (*tsh)[65] = (float(*)[65])shpool;        // 4160 floats <= 4352
        int tt = b - RT_BLKS;
        if (tt < 2048) {                    // W1 [E][512][2048] -> [E][2048][512]
            int bx = tt & 31, by = (tt >> 5) & 7, bz = tt >> 8;
            size_t zoff = (size_t)bz * D_DIM * F_DIM;
            tbody(W1 + zoff, W1T + zoff, D_DIM, F_DIM, bx * 64, by * 64, tid, tsh);
        } else {                            // W2 [E][2048][512] -> [E][512][2048]
            int t2 = tt - 2048;
            int bx = t2 & 7, by = (t2 >> 3) & 31, bz = t2 >> 8;
            size_t zoff = (size_t)bz * D_DIM * F_DIM;
            tbody(W2 + zoff, W2T + zoff, F_DIM, D_DIM, bx * 64, by * 64, tid, tsh);
        }
        return;
    }

    // ---- routing ----
    float* anl = shpool;                    // [e][p*136 + i], i<128
    if (tid < E_EXP) hist[tid] = 0;
    for (int i = tid; i < E_EXP * D_DIM; i += 256) {
        int e = i >> 9, d = i & 511;
        anl[e * 544 + (d >> 7) * 136 + (d & 127)] = anchors[i];
    }
    __syncthreads();
    {   // normalize anchors in LDS: 32 threads per anchor
        int e = tid >> 5, l = tid & 31;
        float ss = 0.f;
        for (int d = l; d < D_DIM; d += 32) {
            float v = anl[e * 544 + (d >> 7) * 136 + (d & 127)];
            ss += v * v;
        }
#pragma unroll
        for (int off = 16; off >= 1; off >>= 1) ss += __shfl_xor(ss, off, 32);
        float inv = 1.0f / fmaxf(sqrtf(ss), 1e-8f);
        for (int d = l; d < D_DIM; d += 32) {
            int ix = e * 544 + (d >> 7) * 136 + (d & 127);
            float nv = anl[ix] * inv;
            anl[ix] = nv;
            if (b == 0) dout_an[e * D_DIM + d] = nv;
        }
    }
    __syncthreads();

    int p = tid & 3;
    int tok = b * 64 + (tid >> 2);
    const float4* xr = (const float4*)(x + (size_t)tok * D_DIM + p * 128);
    const float* ab = &anl[p * 136];
    float dot[E_EXP] = {};
    float ss = 0.f;
    for (int c = 0; c < 32; ++c) {
        float4 xv = xr[c];
        ss += xv.x*xv.x + xv.y*xv.y + xv.z*xv.z + xv.w*xv.w;
#pragma unroll
        for (int e = 0; e < E_EXP; ++e) {
            float4 av = *(const float4*)&ab[e * 544 + c * 4];
            dot[e] += xv.x*av.x + xv.y*av.y + xv.z*av.z + xv.w*av.w;
        }
    }
#pragma unroll
    for (int off = 1; off <= 2; off <<= 1) {
        ss += __shfl_xor(ss, off, 64);
#pragma unroll
        for (int e = 0; e < E_EXP; ++e) dot[e] += __shfl_xor(dot[e], off, 64);
    }

    if (p == 0) {
        float inv = 1.0f / fmaxf(sqrtf(ss), 1e-8f);
        float s[E_EXP];
#pragma unroll
        for (int e = 0; e < E_EXP; ++e) s[e] = dot[e] * inv;
        int i0 = 0; float b0 = s[0];
#pragma unroll
        for (int e = 1; e < E_EXP; ++e) if (s[e] > b0) { b0 = s[e]; i0 = e; }
        int i1 = -1; float b1v = -1e30f;
#pragma unroll
        for (int e = 0; e < E_EXP; ++e)
            if (e != i0 && s[e] > b1v) { b1v = s[e]; i1 = e; }
        if (i1 < 0) { i1 = (i0 + 1) & 7; b1v = s[i1]; }   // NaN-safety
        float g0 = 1.0f / (1.0f + expf(b1v - b0));
        float g1 = 1.0f - g0;
#pragma unroll
        for (int e = 0; e < E_EXP; ++e) dout_scores[tok * E_EXP + e] = s[e];
        dout_idx[tok * 2 + 0] = (float)i0;
        dout_idx[tok * 2 + 1] = (float)i1;
        idxs[tok * 2 + 0] = i0; idxs[tok * 2 + 1] = i1;
        gates[tok * 2 + 0] = g0; gates[tok * 2 + 1] = g1;
        int r0 = atomicAdd(&hist[i0], 1);     // LDS atomic: free in-block rank
        int r1 = atomicAdd(&hist[i1], 1);
        ranks[tok * 2 + 0] = r0;
        ranks[tok * 2 + 1] = r1;
    }
    __syncthreads();
    if (tid < E_EXP) cnthist[b * E_EXP + tid] = hist[tid];
}

// ---------------- scatter_k: ATOMIC-FREE assign + gather --------------------
// 2048 blocks x 4 waves = 8192 waves = one per (token,k) assignment.
// slot = soff[e] + Sum_{rb'<rb} cnthist[rb'][e] (wave reduce) + rank.
// Buckets 256-aligned (for the 256^2 gemm tiles). Block 0 publishes offs.
__global__ void scatter_k(const float* __restrict__ x, const int* __restrict__ cnthist,
                          const int* __restrict__ idxs, const int* __restrict__ ranks,
                          const float* __restrict__ gates, int* __restrict__ offs,
                          int* __restrict__ rowmap, float* __restrict__ rowgate,
                          u16* __restrict__ Xg) {
    __shared__ int soff[E_EXP + 1];
    __shared__ int scnt[E_EXP];
    int tid = threadIdx.x;
    if (tid < E_EXP) {
        int s = 0;
        for (int b = 0; b < RT_BLKS; ++b) s += cnthist[b * E_EXP + tid];
        scnt[tid] = s;
    }
    __syncthreads();
    if (tid == 0) {
        int acc = 0;
        for (int e = 0; e < E_EXP; ++e) { soff[e] = acc; acc += (scnt[e] + 255) & ~255; }
        soff[E_EXP] = acc;
    }
    __syncthreads();
    if (blockIdx.x == 0 && tid <= E_EXP) offs[tid] = soff[tid];

    int w = tid >> 6, lane = tid & 63;
    int p = blockIdx.x * 4 + w;          // assignment 0..8191
    int t = p >> 1, k = p & 1;
    int e = idxs[t * 2 + k];
    e = min(max(e, 0), E_EXP - 1);
    int rb = t >> 6;                     // routing block of token t
    int v = (lane < rb) ? cnthist[lane * E_EXP + e] : 0;
#pragma unroll
    for (int off = 32; off >= 1; off >>= 1) v += __shfl_xor(v, off, 64);
    int r = soff[e] + v + ranks[t * 2 + k];
    if (lane == 0) {
        rowmap[r] = t;
        rowgate[r] = gates[t * 2 + k];
    }
    const float4* xs = (const float4*)(x + (size_t)t * D_DIM + lane * 8);
    float4 v0 = xs[0], v1 = xs[1];
    u16x8 o = { f2b(v0.x), f2b(v0.y), f2b(v0.z), f2b(v0.w),
                f2b(v1.x), f2b(v1.y), f2b(v1.z), f2b(v1.w) };
    *(u16x8*)(Xg + (size_t)r * D_DIM + lane * 8) = o;
}

// ---------------- grouped GEMM: 256^2 tile, T3-minimum 2-phase --------------
// MODE 0: Hg = bf16(gelu(Xg @ W1e^T + b1e))         (N=F, K=D), nT=8
// MODE 1: out[tok] += gate*(Hg @ W2e^T + [z0]b2e)   (N=D, K=F, splitK4), nT=2
// 512 thr = 8 waves (wm 2 x wn 4), 128x64 output per wave, acc[8][4] f32x4.
// LDS = 2 dbuf x (A 256x64 + B 256x64) bf16 = 128KB dynamic, 1 block/CU.
// Schedule (m230-V0 recipe): stage(0); sync; loop { stage(next) FIRST;
// 4 quadrant groups {12 ds_read_b128 -> 16 MFMA, setprio-wrapped};
// __syncthreads (one drain+barrier per K-tile) }. XOR swizzle kc^(row&7):
// global source pre-swizzled, read side XORed (conflict-free b128 reads).
template <int MODE>
__launch_bounds__(512, 1)
__global__ void gemm_k(const u16* __restrict__ A, int lda,
                       const u16* __restrict__ BtBase, int ldb,
                       u16* __restrict__ Hout, const float* __restrict__ b1,
                       float* __restrict__ outm, const float* __restrict__ b2,
                       const int* __restrict__ rowmap, const float* __restrict__ rowgate,
                       const int* __restrict__ offs, int kPer, int nT) {
    int L = blockIdx.x;
    int per = gridDim.x >> 3;
    int tile = (L & 7) * per + (L >> 3);   // XCD swizzle (grid % 8 == 0)
    int z = 0;
    if (MODE == 1) {                 // split-K 4
        int nz = gridDim.x >> 2;     // 80 tiles per z
        z = tile / nz; tile -= z * nz;
    }
    int mtile = tile / nT;
    int n0 = (tile - mtile * nT) * 256;
    int row0 = mtile * 256;
    if (row0 >= offs[E_EXP]) return;
    int e = 0;
#pragma unroll
    for (int i = 1; i < E_EXP; ++i) if (row0 >= offs[i]) e = i;
    const u16* Bt = BtBase + (size_t)e * D_DIM * F_DIM;
    int k_begin = z * kPer;
    int nt = kPer >> 6;              // K-tiles of 64

    extern __shared__ __align__(16) u16 smem[];
    u16* As = smem;                  // [2][256*64]
    u16* Bs = smem + 2 * GTILE;      // [2][256*64]

    int tid = threadIdx.x;
    int lane = tid & 63;
    int wv = tid >> 6;               // 0..7
    int wm = wv & 1;                 // 2 M-halves (128 rows each)
    int wn = wv >> 1;                // 4 N-quarters (64 cols each)
    int kq = lane >> 4;              // quad 0..3
    int l15 = lane & 15;

    // staging: A and B each 4 x 512 slots; slot -> (m = slot>>3, kc = slot&7).
    // LDS dest LINEAR slot*16B; global source column pre-swizzled kc^(m&7).
    const u16* aS[4]; const u16* bS[4]; int dOff[4];
#pragma unroll
    for (int i = 0; i < 4; ++i) {
        int slot = i * 512 + tid;
        int m = slot >> 3;
        int kcs = (slot & 7) ^ (m & 7);
        aS[i] = A + (size_t)(row0 + m) * lda + kcs * 8;
        bS[i] = Bt + (size_t)(n0 + m) * ldb + kcs * 8;
        dOff[i] = slot * 8;
    }

    auto stage = [&](int buf, int k0) {
#pragma unroll
        for (int i = 0; i < 4; ++i) gload16(As + buf * GTILE + dOff[i], aS[i] + k0);
#pragma unroll
        for (int i = 0; i < 4; ++i) gload16(Bs + buf * GTILE + dOff[i], bS[i] + k0);
    };

    f32x4 acc[8][4];
#pragma unroll
    for (int i = 0; i < 8; ++i)
#pragma unroll
        for (int j = 0; j < 4; ++j) acc[i][j] = f32x4{0.f, 0.f, 0.f, 0.f};

    stage(0, k_begin);
    __syncthreads();                 // prologue drain (vmcnt0 + barrier)

    int sx = l15 & 7;                // row&7 == l15&7 (all row bases ≡ 0 mod 16)
    int cur = 0;
    for (int t = 0; t < nt; ++t) {
        if (t + 1 < nt) stage(cur ^ 1, k_begin + (t + 1) * 64);  // issue FIRST
        const u16* Ab = As + cur * GTILE;
        const u16* Bb = Bs + cur * GTILE;
        // 4 quadrant groups: (qm, qn) -> 4 Mfrag x 2 Nfrag x 2 Ksub = 16 MFMA
#pragma unroll
        for (int q = 0; q < 4; ++q) {
            int qm = q >> 1, qn = q & 1;
            bf16x8 af[4][2], bfr[2][2];
#pragma unroll
            for (int i = 0; i < 4; ++i) {
                int rowA = wm * 128 + (qm * 4 + i) * 16 + l15;
#pragma unroll
                for (int kk = 0; kk < 2; ++kk) {
                    int kca = (kk * 4 + kq) ^ sx;
                    af[i][kk] = *(const bf16x8*)(Ab + rowA * 64 + kca * 8);
                }
            }
#pragma unroll
            for (int j = 0; j < 2; ++j) {
                int rowB = wn * 64 + (qn * 2 + j) * 16 + l15;
#pragma unroll
                for (int kk = 0; kk < 2; ++kk) {
                    int kca = (kk * 4 + kq) ^ sx;
                    bfr[j][kk] = *(const bf16x8*)(Bb + rowB * 64 + kca * 8);
                }
            }
            __builtin_amdgcn_s_setprio(1);
#pragma unroll
            for (int i = 0; i < 4; ++i)
#pragma unroll
                for (int j = 0; j < 2; ++j)
#pragma unroll
                    for (int kk = 0; kk < 2; ++kk)
                        acc[qm * 4 + i][qn * 2 + j] =
                            __builtin_amdgcn_mfma_f32_16x16x32_bf16(
                                af[i][kk], bfr[j][kk],
                                acc[qm * 4 + i][qn * 2 + j], 0, 0, 0);
            __builtin_amdgcn_s_setprio(0);
        }
        __syncthreads();   // one drain+barrier per K-tile: next tile landed,
        cur ^= 1;          // and WAR-safe to overwrite buf[cur] next iter
    }

    if constexpr (MODE == 0) {
        const float* b1e = b1 + (size_t)e * F_DIM;
#pragma unroll
        for (int mi = 0; mi < 8; ++mi) {
            int gr = row0 + wm * 128 + mi * 16 + kq * 4;
#pragma unroll
            for (int ni = 0; ni < 4; ++ni) {
                int gc = n0 + wn * 64 + ni * 16 + l15;
                float bb = b1e[gc];
#pragma unroll
                for (int r = 0; r < 4; ++r) {
                    float v = acc[mi][ni][r] + bb;
                    Hout[(size_t)(gr + r) * F_DIM + gc] = f2b(gelu_f(v));
                }
            }
        }
    } else {
        const float* b2e = b2 + (size_t)e * D_DIM;
        bool addBias = (k_begin == 0);
#pragma unroll
        for (int mi = 0; mi < 8; ++mi) {
            int grb = row0 + wm * 128 + mi * 16 + kq * 4;
#pragma unroll
            for (int r = 0; r < 4; ++r) {
                int tok = rowmap[grb + r];
                float g = rowgate[grb + r];
                if (tok >= 0 && tok < T_TOK) {
                    float* orow = outm + (size_t)tok * D_DIM;
#pragma unroll
                    for (int ni = 0; ni < 4; ++ni) {
                        int gc = n0 + wn * 64 + ni * 16 + l15;
                        float bb = addBias ? b2e[gc] : 0.f;
                        atomicAdd(orow + gc, g * (acc[mi][ni][r] + bb));
                    }
                }
            }
        }
    }
}

// ---------------- workspace layout (bytes) — ends 0x5300000 = 83 MB ---------
#define OFF_CNTH    0x10000u     // int[64*8] per-block histograms
#define OFF_OFFS    0x10900u     // int[9]
#define OFF_IDX     0x20000u     // int[T*2]
#define OFF_GATE    0x28000u     // float[T*2]
#define OFF_ROWMAP  0x30000u     // int[NROWS] 40KB
#define OFF_ROWGATE 0x40000u     // float[NROWS] 40KB
#define OFF_RANK    0x50000u     // int[T*2]
#define OFF_XG      0x100000u    // 10.49 MB u16[NROWS*D]   -> ends 0xB00000
#define OFF_W1T     0xB00000u    // 16.78 MB u16[E][F][D]   -> ends 0x1B00000
#define OFF_W2T     0x1B00000u   // 16.78 MB u16[E][D][F]   -> ends 0x2B00000
#define OFF_HG      0x2B00000u   // 41.94 MB u16[NROWS*F]   -> ends 0x5300000

extern "C" void kernel_launch(void* const* d_in, const int* in_sizes, int n_in,
                              void* d_out, int out_size, void* d_ws, size_t ws_size,
                              hipStream_t stream) {
    const float* x       = (const float*)d_in[0];
    const float* anchors = (const float*)d_in[1];
    const float* W1      = (const float*)d_in[2];
    const float* b1      = (const float*)d_in[3];
    const float* W2      = (const float*)d_in[4];
    const float* b2      = (const float*)d_in[5];
    float* out = (float*)d_out;

    char* ws = (char*)d_ws;
    int*   cnthist = (int*)(ws + OFF_CNTH);
    int*   offs    = (int*)(ws + OFF_OFFS);
    int*   idxs    = (int*)(ws + OFF_IDX);
    float* gates   = (float*)(ws + OFF_GATE);
    int*   rowmap  = (int*)(ws + OFF_ROWMAP);
    float* rowgate = (float*)(ws + OFF_ROWGATE);
    int*   ranks   = (int*)(ws + OFF_RANK);
    u16*   Xg      = (u16*)(ws + OFF_XG);
    u16*   W1T     = (u16*)(ws + OFF_W1T);
    u16*   W2T     = (u16*)(ws + OFF_W2T);
    u16*   Hg      = (u16*)(ws + OFF_HG);

    // d_out sections (fp32 elements): out | a_n | scores | topk_idx
    float* out_main   = out;
    float* out_an     = out + (size_t)T_TOK * D_DIM;
    float* out_scores = out_an + E_EXP * D_DIM;
    float* out_idx    = out_scores + (size_t)T_TOK * E_EXP;

    // allow 128 KB dynamic LDS (gfx950: 160 KB/CU); once per process
    static bool attr_done = false;
    if (!attr_done) {
        hipFuncSetAttribute((const void*)gemm_k<0>,
                            hipFuncAttributeMaxDynamicSharedMemorySize, GEMM_LDS);
        hipFuncSetAttribute((const void*)gemm_k<1>,
                            hipFuncAttributeMaxDynamicSharedMemorySize, GEMM_LDS);
        attr_done = true;
    }

    pre_k<<<PRE_BLOCKS, 256, 0, stream>>>(x, anchors, W1, W1T, W2, W2T,
                                          out_main, out_an, out_scores, out_idx,
                                          idxs, gates, cnthist, ranks,
                                          rowmap, rowgate);
    scatter_k<<<2048, 256, 0, stream>>>(x, cnthist, idxs, ranks, gates, offs,
                                        rowmap, rowgate, Xg);
    // gemm1: 8 n-tiles(256) x 40 m-tiles(256) = 320 blocks (XCD-swizzled)
    gemm_k<0><<<G1_TILES, 512, GEMM_LDS, stream>>>(
        Xg, D_DIM, W1T, D_DIM, Hg, b1, nullptr, nullptr,
        rowmap, nullptr, offs, D_DIM, 8);
    // gemm2: 2 n-tiles(256) x 40 m-tiles x splitK4 = 320 blocks
    gemm_k<1><<<G2_TILES, 512, GEMM_LDS, stream>>>(
        Hg, F_DIM, W2T, F_DIM, nullptr, nullptr, out_main, b2,
        rowmap, rowgate, offs, F_DIM / 4, 2);
}

// Round 13
// 221.244 us; speedup vs baseline: 1.4820x; 1.4820x over previous
//
#include <hip/hip_runtime.h>
#include <cstdint>

// ---------------------------------------------------------------------------
// Round 26 = exact revert to r23 (measured 215.5us, session best).
// r25 post-mortem: 256^2/1-block-CU 2-phase FAILED again (151us/gemm,
// MfmaUtil 4.9%, 320 blocks on 256 CUs = 2-round tail). Sixth failed attempt
// to beat the r18/r23 core. Law confirmed: r23's gemms stage 295MB in 59us
// = 5.0 TB/s = the measured chip staging wall for this schedule class; the
// config that sustains it is many small independent gangs (128^2, 256thr,
// 4 blocks/CU, drain-to-0). Banking the optimum.
// ---------------------------------------------------------------------------

#define T_TOK 4096
#define D_DIM 512
#define F_DIM 2048
#define E_EXP 8
#define NROWS 9216      // 8192 assignments + 8*128 pad
#define MAXTILES 72     // NROWS / 128

typedef __bf16 bf16x8 __attribute__((ext_vector_type(8)));
typedef float  f32x4  __attribute__((ext_vector_type(4)));
typedef unsigned short u16;
typedef unsigned short u16x8 __attribute__((ext_vector_type(8)));

__device__ __forceinline__ u16 f2b(float f) {
    return __builtin_bit_cast(unsigned short, (__bf16)f);
}
__device__ __forceinline__ void gload16(void* lds, const void* g) {
    __builtin_amdgcn_global_load_lds(
        (const __attribute__((address_space(1))) void*)g,
        (__attribute__((address_space(3))) void*)lds, 16, 0, 0);
}
// tanh-approx GELU (err ~3e-4 << bf16 ulp)
__device__ __forceinline__ float gelu_f(float v) {
    float z = 0.7978845608f * (v + 0.044715f * v * v * v);
    float t = 1.0f - 2.0f / (1.0f + __expf(2.0f * z));
    return 0.5f * v * (1.0f + t);
}

// ---------------- transpose tile body (shared by pre_k) ---------------------
__device__ __forceinline__ void tbody(const float* __restrict__ in,
                                      u16* __restrict__ out, int R, int C,
                                      int c0, int r0, int tid,
                                      float (*t)[65]) {
    int cq = tid & 15, rb = tid >> 4;
#pragma unroll
    for (int pass = 0; pass < 4; ++pass) {
        int rr = rb + pass * 16;
        float4 v = *(const float4*)(in + (size_t)(r0 + rr) * C + c0 + cq * 4);
        t[rr][cq * 4 + 0] = v.x; t[rr][cq * 4 + 1] = v.y;
        t[rr][cq * 4 + 2] = v.z; t[rr][cq * 4 + 3] = v.w;
    }
    __syncthreads();
    int rg = tid & 15, cb = tid >> 4;
#pragma unroll
    for (int pass = 0; pass < 4; ++pass) {
        int c = cb + pass * 16;
        ushort4 o;
        o.x = f2b(t[rg * 4 + 0][c]); o.y = f2b(t[rg * 4 + 1][c]);
        o.z = f2b(t[rg * 4 + 2][c]); o.w = f2b(t[rg * 4 + 3][c]);
        *(ushort4*)(out + (size_t)(c0 + c) * R + r0 + rg * 4) = o;
    }
}

// ---------------- pre_k: routing + transposes + zero/init, ONE dispatch -----
// [0,64): routing (+ per-assignment ranks)  [64,4160): W1/W2 transpose
// [4160,5184): zero outm   [5184]: rowmap=-1, rowgate=0
#define RT_BLKS 64
#define TR_BLKS 4096
#define ZO_BLKS 1024
#define PRE_BLOCKS (RT_BLKS + TR_BLKS + ZO_BLKS + 1)

__global__ void pre_k(const float* __restrict__ x, const float* __restrict__ anchors,
                      const float* __restrict__ W1, u16* __restrict__ W1T,
                      const float* __restrict__ W2, u16* __restrict__ W2T,
                      float* __restrict__ outm, float* __restrict__ dout_an,
                      float* __restrict__ dout_scores, float* __restrict__ dout_idx,
                      int* __restrict__ idxs, float* __restrict__ gates,
                      int* __restrict__ cnthist, int* __restrict__ ranks,
                      int* __restrict__ rowmap, float* __restrict__ rowgate) {
    __shared__ float shpool[E_EXP * 544];   // routing: anl; transpose: 64x65
    __shared__ int hist[E_EXP];
    int b = blockIdx.x;
    int tid = threadIdx.x;

    if (b >= RT_BLKS + TR_BLKS + ZO_BLKS) {             // ---- misc init ----
        for (int r = tid; r < NROWS; r += 256) {
            rowmap[r] = -1; rowgate[r] = 0.f;
        }
        return;
    }
    if (b >= RT_BLKS + TR_BLKS) {                       // ---- zero outm ----
        int zb = b - (RT_BLKS + TR_BLKS);
        float4* o4 = (float4*)outm;
        int i = zb * 256 + tid;
        o4[i] = float4{0.f, 0.f, 0.f, 0.f};
        o4[i + ZO_BLKS * 256] = float4{0.f, 0.f, 0.f, 0.f};
        return;
    }
    if (b >= RT_BLKS) {                                 // ---- transposes ----
        float (*tsh)[65] = (float(*)[65])shpool;        // 4160 floats <= 4352
        int tt = b - RT_BLKS;
        if (tt < 2048) {                    // W1 [E][512][2048] -> [E][2048][512]
            int bx = tt & 31, by = (tt >> 5) & 7, bz = tt >> 8;
            size_t zoff = (size_t)bz * D_DIM * F_DIM;
            tbody(W1 + zoff, W1T + zoff, D_DIM, F_DIM, bx * 64, by * 64, tid, tsh);
        } else {                            // W2 [E][2048][512] -> [E][512][2048]
            int t2 = tt - 2048;
            int bx = t2 & 7, by = (t2 >> 3) & 31, bz = t2 >> 8;
            size_t zoff = (size_t)bz * D_DIM * F_DIM;
            tbody(W2 + zoff, W2T + zoff, F_DIM, D_DIM, bx * 64, by * 64, tid, tsh);
        }
        return;
    }

    // ---- routing ----
    float* anl = shpool;                    // [e][p*136 + i], i<128
    if (tid < E_EXP) hist[tid] = 0;
    for (int i = tid; i < E_EXP * D_DIM; i += 256) {
        int e = i >> 9, d = i & 511;
        anl[e * 544 + (d >> 7) * 136 + (d & 127)] = anchors[i];
    }
    __syncthreads();
    {   // normalize anchors in LDS: 32 threads per anchor
        int e = tid >> 5, l = tid & 31;
        float ss = 0.f;
        for (int d = l; d < D_DIM; d += 32) {
            float v = anl[e * 544 + (d >> 7) * 136 + (d & 127)];
            ss += v * v;
        }
#pragma unroll
        for (int off = 16; off >= 1; off >>= 1) ss += __shfl_xor(ss, off, 32);
        float inv = 1.0f / fmaxf(sqrtf(ss), 1e-8f);
        for (int d = l; d < D_DIM; d += 32) {
            int ix = e * 544 + (d >> 7) * 136 + (d & 127);
            float nv = anl[ix] * inv;
            anl[ix] = nv;
            if (b == 0) dout_an[e * D_DIM + d] = nv;
        }
    }
    __syncthreads();

    int p = tid & 3;
    int tok = b * 64 + (tid >> 2);
    const float4* xr = (const float4*)(x + (size_t)tok * D_DIM + p * 128);
    const float* ab = &anl[p * 136];
    float dot[E_EXP] = {};
    float ss = 0.f;
    for (int c = 0; c < 32; ++c) {
        float4 xv = xr[c];
        ss += xv.x*xv.x + xv.y*xv.y + xv.z*xv.z + xv.w*xv.w;
#pragma unroll
        for (int e = 0; e < E_EXP; ++e) {
            float4 av = *(const float4*)&ab[e * 544 + c * 4];
            dot[e] += xv.x*av.x + xv.y*av.y + xv.z*av.z + xv.w*av.w;
        }
    }
#pragma unroll
    for (int off = 1; off <= 2; off <<= 1) {
        ss += __shfl_xor(ss, off, 64);
#pragma unroll
        for (int e = 0; e < E_EXP; ++e) dot[e] += __shfl_xor(dot[e], off, 64);
    }

    if (p == 0) {
        float inv = 1.0f / fmaxf(sqrtf(ss), 1e-8f);
        float s[E_EXP];
#pragma unroll
        for (int e = 0; e < E_EXP; ++e) s[e] = dot[e] * inv;
        int i0 = 0; float b0 = s[0];
#pragma unroll
        for (int e = 1; e < E_EXP; ++e) if (s[e] > b0) { b0 = s[e]; i0 = e; }
        int i1 = -1; float b1v = -1e30f;
#pragma unroll
        for (int e = 0; e < E_EXP; ++e)
            if (e != i0 && s[e] > b1v) { b1v = s[e]; i1 = e; }
        if (i1 < 0) { i1 = (i0 + 1) & 7; b1v = s[i1]; }   // NaN-safety
        float g0 = 1.0f / (1.0f + expf(b1v - b0));
        float g1 = 1.0f - g0;
#pragma unroll
        for (int e = 0; e < E_EXP; ++e) dout_scores[tok * E_EXP + e] = s[e];
        dout_idx[tok * 2 + 0] = (float)i0;
        dout_idx[tok * 2 + 1] = (float)i1;
        idxs[tok * 2 + 0] = i0; idxs[tok * 2 + 1] = i1;
        gates[tok * 2 + 0] = g0; gates[tok * 2 + 1] = g1;
        // LDS-hist atomic return value = free within-block rank per expert
        int r0 = atomicAdd(&hist[i0], 1);
        int r1 = atomicAdd(&hist[i1], 1);
        ranks[tok * 2 + 0] = r0;
        ranks[tok * 2 + 1] = r1;
    }
    __syncthreads();
    if (tid < E_EXP) cnthist[b * E_EXP + tid] = hist[tid];
}

// ---------------- scatter_k: ATOMIC-FREE assign + gather --------------------
// 2048 blocks x 4 waves = 8192 waves = one per (token,k) assignment.
// slot = soff[e] + Sum_{rb'<rb} cnthist[rb'][e] (64-lane wave reduce) + rank.
// Then copy x[t] row -> Xg[slot] bf16. Block 0 publishes offs.
__global__ void scatter_k(const float* __restrict__ x, const int* __restrict__ cnthist,
                          const int* __restrict__ idxs, const int* __restrict__ ranks,
                          const float* __restrict__ gates, int* __restrict__ offs,
                          int* __restrict__ rowmap, float* __restrict__ rowgate,
                          u16* __restrict__ Xg) {
    __shared__ int soff[E_EXP + 1];
    __shared__ int scnt[E_EXP];
    int tid = threadIdx.x;
    if (tid < E_EXP) {
        int s = 0;
        for (int b = 0; b < RT_BLKS; ++b) s += cnthist[b * E_EXP + tid];
        scnt[tid] = s;
    }
    __syncthreads();
    if (tid == 0) {
        int acc = 0;
        for (int e = 0; e < E_EXP; ++e) { soff[e] = acc; acc += (scnt[e] + 127) & ~127; }
        soff[E_EXP] = acc;
    }
    __syncthreads();
    if (blockIdx.x == 0 && tid <= E_EXP) offs[tid] = soff[tid];

    int w = tid >> 6, lane = tid & 63;
    int p = blockIdx.x * 4 + w;          // assignment 0..8191
    int t = p >> 1, k = p & 1;
    int e = idxs[t * 2 + k];
    e = min(max(e, 0), E_EXP - 1);
    int rb = t >> 6;                     // routing block of token t
    // exclusive cross-block prefix for expert e: lanes < rb contribute
    int v = (lane < rb) ? cnthist[lane * E_EXP + e] : 0;
#pragma unroll
    for (int off = 32; off >= 1; off >>= 1) v += __shfl_xor(v, off, 64);
    int r = soff[e] + v + ranks[t * 2 + k];
    if (lane == 0) {
        rowmap[r] = t;
        rowgate[r] = gates[t * 2 + k];
    }
    const float4* xs = (const float4*)(x + (size_t)t * D_DIM + lane * 8);
    float4 v0 = xs[0], v1 = xs[1];
    u16x8 o = { f2b(v0.x), f2b(v0.y), f2b(v0.z), f2b(v0.w),
                f2b(v1.x), f2b(v1.y), f2b(v1.z), f2b(v1.w) };
    *(u16x8*)(Xg + (size_t)r * D_DIM + lane * 8) = o;
}

// ---------------- grouped GEMM core (r18's proven core, untouched) ----------
// MODE 0: Hg = bf16(gelu(Xg @ W1e^T + b1e))         (N=F, K=D), NT=16
// MODE 1: out[tok] += gate*(Hg @ W2e^T + [z0]b2e)   (N=D, K=F, split-K=2), NT=4
// 128x128 tile, 256 thr (4 waves, 2m x 2n, 64x64/wave), 32KB static LDS,
// drain-to-0 per K-step; 4 independent gangs/CU do the latency hiding
// (measured 5.0 TB/s staged vs 1.9-2.4 for every low-gang variant).
// XOR col swizzle kc^(row&7): global source pre-swizzled, read side XORed.
template <int MODE>
__launch_bounds__(256, 4)
__global__ void gemm_k(const u16* __restrict__ A, int lda,
                       const u16* __restrict__ BtBase, int ldb,
                       u16* __restrict__ Hout, const float* __restrict__ b1,
                       float* __restrict__ outm, const float* __restrict__ b2,
                       const int* __restrict__ rowmap, const float* __restrict__ rowgate,
                       const int* __restrict__ offs, int kPer, int nT) {
    int L = blockIdx.x;
    int per = gridDim.x >> 3;
    int tile = (L & 7) * per + (L >> 3);
    int z = 0;
    if (MODE == 1) {                 // split-K 2: high half of tiles is z=1
        int half = gridDim.x >> 1;
        z = tile >= half; tile -= z * half;
    }
    int mtile = tile / nT;
    int n0 = (tile - mtile * nT) * 128;
    int row0 = mtile * 128;
    if (row0 >= offs[E_EXP]) return;
    int e = 0;
#pragma unroll
    for (int i = 1; i < E_EXP; ++i) if (row0 >= offs[i]) e = i;
    const u16* Bt = BtBase + (size_t)e * D_DIM * F_DIM;
    int k_begin = z * kPer;
    int k_end = k_begin + kPer;

    alignas(16) __shared__ u16 As[128 * 64];
    alignas(16) __shared__ u16 Bs[128 * 64];

    int tid = threadIdx.x;
    int lane = tid & 63;
    int wv = tid >> 6;
    int wm = wv & 1, wn = wv >> 1;
    int kq = lane >> 4;          // quad 0..3
    int l15 = lane & 15;

    // staging: slot = i*256 + tid; m = slot>>3; kc = slot&7.
    // LDS dest LINEAR slot*16B; global source column pre-swizzled kc^(m&7).
    const u16* aSrc[4]; const u16* bSrc[4];
    u16* aDst[4]; u16* bDst[4];
#pragma unroll
    for (int i = 0; i < 4; ++i) {
        int slot = i * 256 + tid;
        int m = slot >> 3;
        int kc = slot & 7;
        int kcs = kc ^ (m & 7);
        aSrc[i] = A + (size_t)(row0 + m) * lda + kcs * 8;
        bSrc[i] = Bt + (size_t)(n0 + m) * ldb + kcs * 8;
        aDst[i] = As + slot * 8;
        bDst[i] = Bs + slot * 8;
    }

    f32x4 acc[4][4];
#pragma unroll
    for (int i = 0; i < 4; ++i)
#pragma unroll
        for (int j = 0; j < 4; ++j) acc[i][j] = f32x4{0.f, 0.f, 0.f, 0.f};

    int sx = l15 & 7;            // row&7 == l15&7 (wm*64, i*16 ≡ 0 mod 8)
    for (int k0 = k_begin; k0 < k_end; k0 += 64) {
#pragma unroll
        for (int i = 0; i < 4; ++i) gload16(aDst[i], aSrc[i] + k0);
#pragma unroll
        for (int i = 0; i < 4; ++i) gload16(bDst[i], bSrc[i] + k0);
        asm volatile("s_waitcnt vmcnt(0)" ::: "memory");
        __syncthreads();
#pragma unroll
        for (int kk = 0; kk < 2; ++kk) {
            int kc = kk * 4 + kq;
            int kca = kc ^ sx;   // swizzled column on the read side
            bf16x8 af[4], bfr[4];
#pragma unroll
            for (int i = 0; i < 4; ++i) {
                int rowA = wm * 64 + i * 16 + l15;
                af[i] = *(const bf16x8*)(As + rowA * 64 + kca * 8);
                int rowB = wn * 64 + i * 16 + l15;
                bfr[i] = *(const bf16x8*)(Bs + rowB * 64 + kca * 8);
            }
#pragma unroll
            for (int i = 0; i < 4; ++i)
#pragma unroll
                for (int j = 0; j < 4; ++j)
                    acc[i][j] = __builtin_amdgcn_mfma_f32_16x16x32_bf16(
                        af[i], bfr[j], acc[i][j], 0, 0, 0);
        }
        __syncthreads();
    }

    if constexpr (MODE == 0) {
        const float* b1e = b1 + (size_t)e * F_DIM;
#pragma unroll
        for (int i = 0; i < 4; ++i) {
            int gr = row0 + wm * 64 + i * 16 + kq * 4;
#pragma unroll
            for (int j = 0; j < 4; ++j) {
                int gc = n0 + wn * 64 + j * 16 + l15;
                float bb = b1e[gc];
#pragma unroll
                for (int r = 0; r < 4; ++r) {
                    float v = acc[i][j][r] + bb;
                    Hout[(size_t)(gr + r) * F_DIM + gc] = f2b(gelu_f(v));
                }
            }
        }
    } else {
        const float* b2e = b2 + (size_t)e * D_DIM;
        bool addBias = (k_begin == 0);
#pragma unroll
        for (int i = 0; i < 4; ++i) {
            int grb = row0 + wm * 64 + i * 16 + kq * 4;
#pragma unroll
            for (int r = 0; r < 4; ++r) {
                int tok = rowmap[grb + r];
                float g = rowgate[grb + r];
                if (tok >= 0 && tok < T_TOK) {
                    float* orow = outm + (size_t)tok * D_DIM;
#pragma unroll
                    for (int j = 0; j < 4; ++j) {
                        int gc = n0 + wn * 64 + j * 16 + l15;
                        float bb = addBias ? b2e[gc] : 0.f;
                        atomicAdd(orow + gc, g * (acc[i][j][r] + bb));
                    }
                }
            }
        }
    }
}

// ---------------- workspace layout (bytes) ----------------------------------
#define OFF_CNTH    0x10000u     // int[64*8] per-block histograms
#define OFF_OFFS    0x10900u     // int[9]
#define OFF_IDX     0x20000u     // int[T*2]
#define OFF_GATE    0x28000u     // float[T*2]
#define OFF_ROWMAP  0x30000u     // int[NROWS]
#define OFF_ROWGATE 0x40000u     // float[NROWS]
#define OFF_RANK    0x50000u     // int[T*2] within-block ranks
#define OFF_XG      0x900000u    // 9.44 MB u16[NROWS*D]  -> ends 0x1200000
#define OFF_W1T     0x1200000u   // 16.78 MB u16[E][F][D] -> ends 0x2200000
#define OFF_W2T     0x2200000u   // 16.78 MB u16[E][D][F] -> ends 0x3200000
#define OFF_HG      0x3200000u   // 37.75 MB u16[NROWS*F] -> ends 0x5600000

extern "C" void kernel_launch(void* const* d_in, const int* in_sizes, int n_in,
                              void* d_out, int out_size, void* d_ws, size_t ws_size,
                              hipStream_t stream) {
    const float* x       = (const float*)d_in[0];
    const float* anchors = (const float*)d_in[1];
    const float* W1      = (const float*)d_in[2];
    const float* b1      = (const float*)d_in[3];
    const float* W2      = (const float*)d_in[4];
    const float* b2      = (const float*)d_in[5];
    float* out = (float*)d_out;

    char* ws = (char*)d_ws;
    int*   cnthist = (int*)(ws + OFF_CNTH);
    int*   offs    = (int*)(ws + OFF_OFFS);
    int*   idxs    = (int*)(ws + OFF_IDX);
    float* gates   = (float*)(ws + OFF_GATE);
    int*   rowmap  = (int*)(ws + OFF_ROWMAP);
    float* rowgate = (float*)(ws + OFF_ROWGATE);
    int*   ranks   = (int*)(ws + OFF_RANK);
    u16*   Xg      = (u16*)(ws + OFF_XG);
    u16*   W1T     = (u16*)(ws + OFF_W1T);
    u16*   W2T     = (u16*)(ws + OFF_W2T);
    u16*   Hg      = (u16*)(ws + OFF_HG);

    // d_out sections (fp32 elements): out | a_n | scores | topk_idx
    float* out_main   = out;
    float* out_an     = out + (size_t)T_TOK * D_DIM;
    float* out_scores = out_an + E_EXP * D_DIM;
    float* out_idx    = out_scores + (size_t)T_TOK * E_EXP;

    pre_k<<<PRE_BLOCKS, 256, 0, stream>>>(x, anchors, W1, W1T, W2, W2T,
                                          out_main, out_an, out_scores, out_idx,
                                          idxs, gates, cnthist, ranks,
                                          rowmap, rowgate);
    scatter_k<<<2048, 256, 0, stream>>>(x, cnthist, idxs, ranks, gates, offs,
                                        rowmap, rowgate, Xg);
    // gemm1: 16 n-tiles x 72 m-tiles = 1152 blocks (1D, XCD-swizzled)
    gemm_k<0><<<16 * MAXTILES, 256, 0, stream>>>(
        Xg, D_DIM, W1T, D_DIM, Hg, b1, nullptr, nullptr,
        rowmap, nullptr, offs, D_DIM, 16);
    // gemm2: 4 n-tiles x 72 m-tiles x splitK2 = 576 blocks (1D, XCD-swizzled)
    gemm_k<1><<<4 * MAXTILES * 2, 256, 0, stream>>>(
        Hg, F_DIM, W2T, F_DIM, nullptr, nullptr, out_main, b2,
        rowmap, rowgate, offs, F_DIM / 2, 4);
}